// Round 3
// baseline (280.074 us; speedup 1.0000x reference)
//
#include <hip/hip_runtime.h>
#include <hip/hip_bf16.h>
#include <hip/hip_cooperative_groups.h>

namespace cg = cooperative_groups;

typedef float f32x4 __attribute__((ext_vector_type(4)));

#define E_DIM 1024   // embed dim (output cols)
#define F_DIM 4096   // ffn dim
#define NBLK  1024   // one block per output element; 4 blocks/CU co-resident
#define NTHR  256

// Fused: phase 1 computes o[e] = w_out[e,:] . relu(w2 @ q) with one block per
// e (4 waves split the 4096-dot); grid.sync(); phase 2 broadcasts o over all
// 16384 rows with nontemporal float4 stores.
// q = analytic 4-qubit circuit expvals; x/w1 are a dead path (RZ phase on |0>).
__global__ __launch_bounds__(256) void qff_fused(
    const float* __restrict__ w2,      // (4096, 4) row-major
    const float* __restrict__ wout,    // (1024, 4096) row-major
    const float* __restrict__ params,  // (4,)
    float* __restrict__ o,             // (1024,) scratch in d_ws
    float* __restrict__ out,           // (B*S, 1024)
    int n4)                            // out_size/4 float4s
{
    __shared__ float psum[4];
    const int t = threadIdx.x;
    const int wave = t >> 6;
    const int lane = t & 63;
    const int e = blockIdx.x;          // output element owned by this block

    // ---- phase 1: o[e] ----
    const float c0 = cosf(params[0]);
    const float c1 = cosf(params[1]);
    const float c2 = cosf(params[2]);
    const float c3 = cosf(params[3]);
    const float q0 = c1 * c2 * c3;
    const float q1 = c0 * c1;
    const float q2 = q1 * c2;
    const float q3 = q2 * c3;

    const f32x4* wrow = reinterpret_cast<const f32x4*>(wout + (size_t)e * F_DIM);
    const f32x4* w2v  = reinterpret_cast<const f32x4*>(w2);  // row g of w2

    float s = 0.0f;
#pragma unroll
    for (int j = 0; j < 4; ++j) {
        const int g4 = wave * 256 + j * 64 + lane;  // float4-group in [0,1024)
        f32x4 a  = wrow[g4];                        // w_out[e, 4g4 .. 4g4+3] (HBM)
        f32x4 r0 = w2v[4 * g4 + 0];                 // w2 rows (64 KB, L2-hit)
        f32x4 r1 = w2v[4 * g4 + 1];
        f32x4 r2 = w2v[4 * g4 + 2];
        f32x4 r3 = w2v[4 * g4 + 3];
        float h0 = fmaxf(r0.x * q0 + r0.y * q1 + r0.z * q2 + r0.w * q3, 0.0f);
        float h1 = fmaxf(r1.x * q0 + r1.y * q1 + r1.z * q2 + r1.w * q3, 0.0f);
        float h2 = fmaxf(r2.x * q0 + r2.y * q1 + r2.z * q2 + r2.w * q3, 0.0f);
        float h3 = fmaxf(r3.x * q0 + r3.y * q1 + r3.z * q2 + r3.w * q3, 0.0f);
        s += a.x * h0 + a.y * h1 + a.z * h2 + a.w * h3;
    }
#pragma unroll
    for (int off = 32; off > 0; off >>= 1) s += __shfl_down(s, off);
    if (lane == 0) psum[wave] = s;
    __syncthreads();
    if (t == 0) {
        float v = psum[0] + psum[1] + psum[2] + psum[3];
        // agent-scope release: per-XCD L2s are not cross-coherent
        __hip_atomic_store(&o[e], v, __ATOMIC_RELEASE, __HIP_MEMORY_SCOPE_AGENT);
    }

    cg::this_grid().sync();

    // ---- phase 2: broadcast 64 MiB ----
    const int idx = blockIdx.x * NTHR + t;          // [0, 262144)
    const int col4 = idx & (E_DIM / 4 - 1);         // source float4, thread-invariant
    f32x4 v;
    v.x = __hip_atomic_load(&o[col4 * 4 + 0], __ATOMIC_ACQUIRE, __HIP_MEMORY_SCOPE_AGENT);
    v.y = __hip_atomic_load(&o[col4 * 4 + 1], __ATOMIC_ACQUIRE, __HIP_MEMORY_SCOPE_AGENT);
    v.z = __hip_atomic_load(&o[col4 * 4 + 2], __ATOMIC_ACQUIRE, __HIP_MEMORY_SCOPE_AGENT);
    v.w = __hip_atomic_load(&o[col4 * 4 + 3], __ATOMIC_ACQUIRE, __HIP_MEMORY_SCOPE_AGENT);

    f32x4* out4 = reinterpret_cast<f32x4*>(out);
    const int stride = NBLK * NTHR;                 // 262144; 16 iterations
    for (int i = idx; i < n4; i += stride) {
        __builtin_nontemporal_store(v, &out4[i]);
    }
}

extern "C" void kernel_launch(void* const* d_in, const int* in_sizes, int n_in,
                              void* d_out, int out_size, void* d_ws, size_t ws_size,
                              hipStream_t stream) {
    // inputs (setup_inputs order): x, w1, w2, w_out, params — x/w1 never read.
    const float* w2     = (const float*)d_in[2];
    const float* w_out  = (const float*)d_in[3];
    const float* params = (const float*)d_in[4];
    float* o   = (float*)d_ws;     // 1024 floats, fully rewritten every call
    float* out = (float*)d_out;
    int n4 = out_size / 4;

    void* args[] = {&w2, &w_out, &params, &o, &out, &n4};
    hipLaunchCooperativeKernel(reinterpret_cast<void*>(qff_fused),
                               dim3(NBLK), dim3(NTHR), args, 0, stream);
}

// Round 4
// 27.392 us; speedup vs baseline: 10.2245x; 10.2245x over previous
//
#include <hip/hip_runtime.h>
#include <hip/hip_bf16.h>

typedef float f32x4 __attribute__((ext_vector_type(4)));

#define E_DIM 1024   // embed dim (output cols)
#define F_DIM 4096   // ffn dim

// Kernel 1: o[e] = sum_g w_out[e,g] * relu( sum_f w2[g,f] * q[f] )
// One block per output element e (1024 blocks). 4 waves split the 4096-long
// dot; pure register compute, one __syncthreads for the LDS combine.
// q = analytic 4-qubit circuit expvals; x/w1 are a dead path (RZ on |0> is a
// global phase -> never read, saves 64 MiB of input traffic).
__global__ __launch_bounds__(256) void qff_head(
    const float* __restrict__ w2,      // (4096, 4) row-major
    const float* __restrict__ wout,    // (1024, 4096) row-major
    const float* __restrict__ params,  // (4,)
    float* __restrict__ o)             // (1024,) in d_ws
{
    __shared__ float psum[4];
    const int t = threadIdx.x;
    const int wave = t >> 6;
    const int lane = t & 63;
    const int e = blockIdx.x;

    const float c0 = cosf(params[0]);
    const float c1 = cosf(params[1]);
    const float c2 = cosf(params[2]);
    const float c3 = cosf(params[3]);
    const float q0 = c1 * c2 * c3;
    const float q1 = c0 * c1;
    const float q2 = q1 * c2;
    const float q3 = q2 * c3;

    const f32x4* wrow = reinterpret_cast<const f32x4*>(wout + (size_t)e * F_DIM);
    const f32x4* w2v  = reinterpret_cast<const f32x4*>(w2);

    float s = 0.0f;
#pragma unroll
    for (int j = 0; j < 4; ++j) {
        const int g4 = wave * 256 + j * 64 + lane;  // float4-group in [0,1024)
        // w_out row: read-once data -> nontemporal (don't evict w2 from L2)
        f32x4 a  = __builtin_nontemporal_load(&wrow[g4]);
        f32x4 r0 = w2v[4 * g4 + 0];                 // w2: 64 KB, L2-resident
        f32x4 r1 = w2v[4 * g4 + 1];
        f32x4 r2 = w2v[4 * g4 + 2];
        f32x4 r3 = w2v[4 * g4 + 3];
        float h0 = fmaxf(r0.x * q0 + r0.y * q1 + r0.z * q2 + r0.w * q3, 0.0f);
        float h1 = fmaxf(r1.x * q0 + r1.y * q1 + r1.z * q2 + r1.w * q3, 0.0f);
        float h2 = fmaxf(r2.x * q0 + r2.y * q1 + r2.z * q2 + r2.w * q3, 0.0f);
        float h3 = fmaxf(r3.x * q0 + r3.y * q1 + r3.z * q2 + r3.w * q3, 0.0f);
        s += a.x * h0 + a.y * h1 + a.z * h2 + a.w * h3;
    }
#pragma unroll
    for (int off = 32; off > 0; off >>= 1) s += __shfl_down(s, off);
    if (lane == 0) psum[wave] = s;
    __syncthreads();
    if (t == 0) o[e] = psum[0] + psum[1] + psum[2] + psum[3];
}

// Kernel 2: out[r, :] = o[:] for all 16384 rows — pure streaming broadcast.
// Grid stride (2048*256 float4s) is a multiple of 256 (= E_DIM/4), so each
// thread's source float4 is invariant: load once, 8 nontemporal stores.
__global__ __launch_bounds__(256) void qff_bcast(
    const float* __restrict__ o, float* __restrict__ out, int n4)
{
    const f32x4* o4 = reinterpret_cast<const f32x4*>(o);
    f32x4* out4 = reinterpret_cast<f32x4*>(out);
    const int stride = gridDim.x * 256;
    const int idx = blockIdx.x * 256 + threadIdx.x;
    const f32x4 v = o4[idx & (E_DIM / 4 - 1)];
    for (int i = idx; i < n4; i += stride) {
        __builtin_nontemporal_store(v, &out4[i]);
    }
}

extern "C" void kernel_launch(void* const* d_in, const int* in_sizes, int n_in,
                              void* d_out, int out_size, void* d_ws, size_t ws_size,
                              hipStream_t stream) {
    // inputs (setup_inputs order): x, w1, w2, w_out, params — x/w1 never read.
    const float* w2     = (const float*)d_in[2];
    const float* w_out  = (const float*)d_in[3];
    const float* params = (const float*)d_in[4];
    float* o   = (float*)d_ws;    // 1024 floats of scratch, rewritten every call
    float* out = (float*)d_out;

    qff_head<<<E_DIM, 256, 0, stream>>>(w2, w_out, params, o);

    const int n4 = out_size / 4;  // 4,194,304 float4 stores = 64 MiB
    qff_bcast<<<2048, 256, 0, stream>>>(o, out, n4);
}

// Round 5
// 26.924 us; speedup vs baseline: 10.4024x; 1.0174x over previous
//
#include <hip/hip_runtime.h>
#include <hip/hip_bf16.h>

typedef float f32x4 __attribute__((ext_vector_type(4)));

#define E_DIM 1024   // embed dim (output cols)
#define F_DIM 4096   // ffn dim

// Kernel 1: o[e] = sum_g w_out[e,g] * relu( sum_f w2[g,f] * q[f] )
// One block per output element e (1024 blocks). 4 waves split the 4096-long
// dot; pure register compute, one __syncthreads for the LDS combine.
// q = analytic 4-qubit circuit expvals; x/w1 are a dead path (RZ on |0> is a
// global phase -> never read, saves 64 MiB of input traffic).
__global__ __launch_bounds__(256) void qff_head(
    const float* __restrict__ w2,      // (4096, 4) row-major
    const float* __restrict__ wout,    // (1024, 4096) row-major
    const float* __restrict__ params,  // (4,)
    float* __restrict__ o)             // (1024,) in d_ws
{
    __shared__ float psum[4];
    const int t = threadIdx.x;
    const int wave = t >> 6;
    const int lane = t & 63;
    const int e = blockIdx.x;

    const float c0 = cosf(params[0]);
    const float c1 = cosf(params[1]);
    const float c2 = cosf(params[2]);
    const float c3 = cosf(params[3]);
    const float q0 = c1 * c2 * c3;
    const float q1 = c0 * c1;
    const float q2 = q1 * c2;
    const float q3 = q2 * c3;

    const f32x4* wrow = reinterpret_cast<const f32x4*>(wout + (size_t)e * F_DIM);
    const f32x4* w2v  = reinterpret_cast<const f32x4*>(w2);

    float s = 0.0f;
#pragma unroll
    for (int j = 0; j < 4; ++j) {
        const int g4 = wave * 256 + j * 64 + lane;  // float4-group in [0,1024)
        // w_out row: read-once data -> nontemporal (don't evict w2 from L2)
        f32x4 a  = __builtin_nontemporal_load(&wrow[g4]);
        f32x4 r0 = w2v[4 * g4 + 0];                 // w2: 64 KB, L2-resident
        f32x4 r1 = w2v[4 * g4 + 1];
        f32x4 r2 = w2v[4 * g4 + 2];
        f32x4 r3 = w2v[4 * g4 + 3];
        float h0 = fmaxf(r0.x * q0 + r0.y * q1 + r0.z * q2 + r0.w * q3, 0.0f);
        float h1 = fmaxf(r1.x * q0 + r1.y * q1 + r1.z * q2 + r1.w * q3, 0.0f);
        float h2 = fmaxf(r2.x * q0 + r2.y * q1 + r2.z * q2 + r2.w * q3, 0.0f);
        float h3 = fmaxf(r3.x * q0 + r3.y * q1 + r3.z * q2 + r3.w * q3, 0.0f);
        s += a.x * h0 + a.y * h1 + a.z * h2 + a.w * h3;
    }
#pragma unroll
    for (int off = 32; off > 0; off >>= 1) s += __shfl_down(s, off);
    if (lane == 0) psum[wave] = s;
    __syncthreads();
    if (t == 0) o[e] = psum[0] + psum[1] + psum[2] + psum[3];
}

// Kernel 2: out[r, :] = o[:] for all 16384 rows — pure streaming broadcast.
// A/B vs round 4: PLAIN temporal stores (the harness fill kernel hits
// 6.8 TB/s with plain stores; testing whether NT streaming is de-rated).
// 4096 blocks x 256 threads x 4 fully-unrolled grid-stride float4 stores;
// every store instruction is 1 KiB/wave contiguous. Grid stride is a
// multiple of 256 float4s so each thread's source element is invariant.
__global__ __launch_bounds__(256) void qff_bcast(
    const float* __restrict__ o, float* __restrict__ out)
{
    const f32x4* o4 = reinterpret_cast<const f32x4*>(o);
    f32x4* out4 = reinterpret_cast<f32x4*>(out);
    const int idx = blockIdx.x * 256 + threadIdx.x;   // [0, 1048576)
    const f32x4 v = o4[idx & (E_DIM / 4 - 1)];
#pragma unroll
    for (int k = 0; k < 4; ++k) {
        out4[idx + k * 1048576] = v;
    }
}

extern "C" void kernel_launch(void* const* d_in, const int* in_sizes, int n_in,
                              void* d_out, int out_size, void* d_ws, size_t ws_size,
                              hipStream_t stream) {
    // inputs (setup_inputs order): x, w1, w2, w_out, params — x/w1 never read.
    const float* w2     = (const float*)d_in[2];
    const float* w_out  = (const float*)d_in[3];
    const float* params = (const float*)d_in[4];
    float* o   = (float*)d_ws;    // 1024 floats of scratch, rewritten every call
    float* out = (float*)d_out;

    qff_head<<<E_DIM, 256, 0, stream>>>(w2, w_out, params, o);

    // out_size = 16384*1024 = 16,777,216 floats = 4,194,304 float4s
    qff_bcast<<<4096, 256, 0, stream>>>(o, out);
}